// Round 5
// baseline (446.983 us; speedup 1.0000x reference)
//
#include <hip/hip_runtime.h>
#include <hip/hip_bf16.h>

// GCN 3-layer forward on gfx950, dtype-robust.
// flags[0]=1 if floats are f32 (else bf16); flags[1]=1 if edges int64 (else int32).
// Pipeline: detect -> memset cnt -> count_edges -> deg_reduce -> scan_bsums
//           -> write_off -> fill_csr -> [gemm_scale -> aggregate] x3
// In the bf16 world, the gathered message buffer G is stored bf16 (halves
// gather bytes + L2 footprint); h intermediates stay f32. f32 world keeps
// f32 G. Aggregate: cooperative 64-edge index fetch + 16-wide unrolled
// gather with fma masking (16 row-loads in flight per wave).

__device__ __forceinline__ float tof(float v) { return v; }
__device__ __forceinline__ float tof(__hip_bfloat16 v) { return __bfloat162float(v); }
__device__ __forceinline__ float bits2f(unsigned u) {
    union { unsigned u; float f; } c; c.u = u; return c.f;
}
__device__ __forceinline__ unsigned short f2bfu(float v) {
    __hip_bfloat16 h = __float2bfloat16(v);
    union { __hip_bfloat16 h; unsigned short u; } c; c.h = h; return c.u;
}

__global__ void detect_dtypes(const void* __restrict__ x,
                              const void* __restrict__ ei,
                              int* __restrict__ flags) {
    const int t = threadIdx.x;
    const int lane = t & 63;
    if (t < 64) {
        const unsigned short* p = (const unsigned short*)x;
        int e = (p[2 * (lane * 16)] >> 7) & 0xFF;
        unsigned long long m = __ballot(e < 100 || e > 140);
        if (lane == 0) flags[0] = (__popcll(m) > 16) ? 1 : 0;
    } else if (t < 128) {
        const int* p = (const int*)ei;
        unsigned long long m = __ballot(p[2 * (lane * 16) + 1] != 0);
        if (lane == 0) flags[1] = (__popcll(m) < 2) ? 1 : 0;
    }
}

__device__ __forceinline__ int edge_at(const void* ei, long long idx, bool i64) {
    return i64 ? (int)((const long long*)ei)[idx] : ((const int*)ei)[idx];
}

__global__ void count_edges(const void* __restrict__ ei, int* __restrict__ cnt,
                            const int* __restrict__ flags, int e) {
    int i = blockIdx.x * 256 + threadIdx.x;
    if (i < e) {
        const bool i64 = flags[1] != 0;
        atomicAdd(&cnt[edge_at(ei, (long long)e + i, i64)], 1);
    }
}

__global__ __launch_bounds__(256) void deg_reduce(const int* __restrict__ cnt,
                                                  int* __restrict__ bsum, int n) {
    __shared__ int sm[4];
    const int t = threadIdx.x;
    int i = blockIdx.x * 256 + t;
    int v = (i < n) ? cnt[i] : 0;
#pragma unroll
    for (int d = 32; d >= 1; d >>= 1) v += __shfl_down(v, d);
    if ((t & 63) == 0) sm[t >> 6] = v;
    __syncthreads();
    if (t == 0) bsum[blockIdx.x] = sm[0] + sm[1] + sm[2] + sm[3];
}

__global__ __launch_bounds__(256) void scan_bsums(int* __restrict__ bsum, int nb) {
    __shared__ int sm[256];
    const int t = threadIdx.x;
    sm[t] = (t < nb) ? bsum[t] : 0;
    __syncthreads();
#pragma unroll
    for (int d = 1; d < 256; d <<= 1) {
        int v = (t >= d) ? sm[t - d] : 0;
        __syncthreads();
        sm[t] += v;
        __syncthreads();
    }
    if (t < nb) bsum[t] = (t == 0) ? 0 : sm[t - 1];
}

__global__ __launch_bounds__(256) void write_off(const int* __restrict__ cnt,
                                                 const int* __restrict__ bsum,
                                                 int* __restrict__ off,
                                                 int* __restrict__ cur,
                                                 float* __restrict__ dinv,
                                                 int n, int e_total) {
    __shared__ int sm[256];
    const int t = threadIdx.x;
    const int i = blockIdx.x * 256 + t;
    const int c = (i < n) ? cnt[i] : 0;
    sm[t] = c;
    __syncthreads();
#pragma unroll
    for (int d = 1; d < 256; d <<= 1) {
        int v = (t >= d) ? sm[t - d] : 0;
        __syncthreads();
        sm[t] += v;
        __syncthreads();
    }
    if (i < n) {
        int o = bsum[blockIdx.x] + sm[t] - c;
        off[i] = o;
        cur[i] = o;
        dinv[i] = rsqrtf((float)(c + 1));
        if (i == n - 1) off[n] = e_total;
    }
}

__global__ void fill_csr(const void* __restrict__ ei, int* __restrict__ cur,
                         int* __restrict__ csr_src, const int* __restrict__ flags, int e) {
    int i = blockIdx.x * 256 + threadIdx.x;
    if (i < e) {
        const bool i64 = flags[1] != 0;
        int r = edge_at(ei, i, i64);
        int c = edge_at(ei, (long long)e + i, i64);
        int p = atomicAdd(&cur[c], 1);
        csr_src[p] = r;
    }
}

// G[i][c] = dinv[i] * sum_k X[i][k]*W[k][c]. 256 threads, 16 rows x COUT/blk.
// G stored bf16 in the bf16 world, f32 in the f32 world.
template <bool XFLAG, int COUT>
__global__ __launch_bounds__(256) void gemm_scale(const void* __restrict__ Xv,
                                                  const void* __restrict__ Wv,
                                                  const float* __restrict__ dinv,
                                                  void* __restrict__ Gv,
                                                  const int* __restrict__ flags, int n) {
    constexpr int ROWS = 16;
    constexpr int KC = 64;
    __shared__ float wlds[KC * COUT];
    __shared__ float xlds[ROWS * 128];
    const int t = threadIdx.x;
    const int row0 = blockIdx.x * ROWS;
    const bool f32 = flags[0] != 0;
    const bool xf32 = XFLAG ? f32 : true;

    if (xf32) {
        const float* X = (const float*)Xv;
        for (int i = t; i < ROWS * 128; i += 256) {
            int r = i >> 7;
            xlds[i] = (row0 + r < n) ? X[(size_t)(row0 + r) * 128 + (i & 127)] : 0.f;
        }
    } else {
        const __hip_bfloat16* X = (const __hip_bfloat16*)Xv;
        for (int i = t; i < ROWS * 128; i += 256) {
            int r = i >> 7;
            xlds[i] = (row0 + r < n) ? tof(X[(size_t)(row0 + r) * 128 + (i & 127)]) : 0.f;
        }
    }

    float acc[8];
#pragma unroll
    for (int j = 0; j < 8; ++j) acc[j] = 0.f;

    const int c4 = (COUT == 128) ? ((t & 31) * 4) : ((t & 15) * 4);
    const int r0 = (COUT == 128) ? ((t >> 5) * 2) : (t >> 4);

    for (int kc = 0; kc < 128; kc += KC) {
        __syncthreads();
        if (f32) {
            const float* W = (const float*)Wv;
            for (int i = t; i < KC * COUT; i += 256)
                wlds[i] = W[(size_t)kc * COUT + i];
        } else {
            const __hip_bfloat16* W = (const __hip_bfloat16*)Wv;
            for (int i = t; i < KC * COUT; i += 256)
                wlds[i] = tof(W[(size_t)kc * COUT + i]);
        }
        __syncthreads();
#pragma unroll
        for (int k = 0; k < KC; ++k) {
            const float4 w = *(const float4*)&wlds[k * COUT + c4];
            if (COUT == 128) {
                float x0 = xlds[r0 * 128 + kc + k];
                float x1 = xlds[(r0 + 1) * 128 + kc + k];
                acc[0] += x0 * w.x; acc[1] += x0 * w.y;
                acc[2] += x0 * w.z; acc[3] += x0 * w.w;
                acc[4] += x1 * w.x; acc[5] += x1 * w.y;
                acc[6] += x1 * w.z; acc[7] += x1 * w.w;
            } else {
                float x0 = xlds[r0 * 128 + kc + k];
                acc[0] += x0 * w.x; acc[1] += x0 * w.y;
                acc[2] += x0 * w.z; acc[3] += x0 * w.w;
            }
        }
    }

    const int nr = (COUT == 128) ? 2 : 1;
#pragma unroll
    for (int rr = 0; rr < nr; ++rr) {
        int row = row0 + r0 + rr;
        if (row < n) {
            float d = dinv[row];
            float o0 = d * acc[rr * 4 + 0];
            float o1 = d * acc[rr * 4 + 1];
            float o2 = d * acc[rr * 4 + 2];
            float o3 = d * acc[rr * 4 + 3];
            if (f32) {
                float4 o = make_float4(o0, o1, o2, o3);
                *(float4*)&((float*)Gv)[(size_t)row * COUT + c4] = o;
            } else {
                ushort4 u;
                u.x = f2bfu(o0); u.y = f2bfu(o1);
                u.z = f2bfu(o2); u.w = f2bfu(o3);
                *(ushort4*)&((unsigned short*)Gv)[(size_t)row * COUT + c4] = u;
            }
        }
    }
}

// One wave per destination node; lane handles CPL channels (CPL*64 == C).
template <int CPL, bool RELU, bool WWS, bool WOUT>
__global__ __launch_bounds__(256) void aggregate(const void* __restrict__ Gv,
                                                 const int* __restrict__ off,
                                                 const int* __restrict__ csr_src,
                                                 const float* __restrict__ dinv,
                                                 const void* __restrict__ bias,
                                                 float* __restrict__ Hf,
                                                 void* __restrict__ outp,
                                                 long long out_off,
                                                 const int* __restrict__ flags, int n) {
    const int gw = (int)((blockIdx.x * 256u + threadIdx.x) >> 6);
    const int lane = threadIdx.x & 63;
    if (gw >= n) return;
    constexpr int C = CPL * 64;
    const size_t base = (size_t)gw * C + lane * CPL;
    const bool f32 = flags[0] != 0;
    const int col = lane * CPL;
    const int e0 = off[gw];
    const int e1 = off[gw + 1];

    float a0, a1;

    if (!f32) {
        // ---- bf16 G path (bench world) ----
        const unsigned short* Gb = (const unsigned short*)Gv;
        if constexpr (CPL == 2) {
            unsigned v = *(const unsigned*)&Gb[base];
            a0 = bits2f(v << 16);
            a1 = bits2f(v & 0xffff0000u);
        } else {
            a0 = bits2f((unsigned)Gb[base] << 16);
            a1 = 0.f;
        }
        for (int bs = e0; bs < e1; bs += 64) {
            const int cnt = min(64, e1 - bs);
            const int myidx = (bs + lane < e1) ? csr_src[bs + lane] : 0;
            for (int j = 0; j < cnt; j += 16) {
#pragma unroll
                for (int k = 0; k < 16; ++k) {
                    const int jj = min(j + k, cnt - 1);
                    const int s = __shfl(myidx, jj);
                    const float m = (j + k < cnt) ? 1.f : 0.f;
                    if constexpr (CPL == 2) {
                        unsigned v = *(const unsigned*)&Gb[(size_t)s * C + col];
                        a0 = fmaf(m, bits2f(v << 16), a0);
                        a1 = fmaf(m, bits2f(v & 0xffff0000u), a1);
                    } else {
                        unsigned short u = Gb[(size_t)s * C + col];
                        a0 = fmaf(m, bits2f((unsigned)u << 16), a0);
                    }
                }
            }
        }
    } else {
        // ---- f32 G path ----
        const float* Gf = (const float*)Gv;
        if constexpr (CPL == 2) {
            float2 v = *(const float2*)&Gf[base];
            a0 = v.x; a1 = v.y;
        } else {
            a0 = Gf[base]; a1 = 0.f;
        }
        for (int bs = e0; bs < e1; bs += 64) {
            const int cnt = min(64, e1 - bs);
            const int myidx = (bs + lane < e1) ? csr_src[bs + lane] : 0;
            for (int j = 0; j < cnt; j += 8) {
#pragma unroll
                for (int k = 0; k < 8; ++k) {
                    const int jj = min(j + k, cnt - 1);
                    const int s = __shfl(myidx, jj);
                    const float m = (j + k < cnt) ? 1.f : 0.f;
                    if constexpr (CPL == 2) {
                        float2 v = *(const float2*)&Gf[(size_t)s * C + col];
                        a0 = fmaf(m, v.x, a0);
                        a1 = fmaf(m, v.y, a1);
                    } else {
                        float v = Gf[(size_t)s * C + col];
                        a0 = fmaf(m, v, a0);
                    }
                }
            }
        }
    }

    const float d = dinv[gw];
    float accs[2] = {a0, a1};
    float o[CPL];
#pragma unroll
    for (int j = 0; j < CPL; ++j) {
        float bv = f32 ? ((const float*)bias)[col + j]
                       : tof(((const __hip_bfloat16*)bias)[col + j]);
        o[j] = d * accs[j] + bv;
        if (RELU) o[j] = fmaxf(o[j], 0.f);
    }
    if constexpr (WWS) {
        if constexpr (CPL == 2)
            *(float2*)&Hf[base] = make_float2(o[0], o[1]);
        else
            Hf[base] = o[0];
    }
    if constexpr (WOUT) {
        if (f32) {
            float* po = (float*)outp + out_off + base;
#pragma unroll
            for (int j = 0; j < CPL; ++j) po[j] = o[j];
        } else {
            __hip_bfloat16* po = (__hip_bfloat16*)outp + out_off + base;
#pragma unroll
            for (int j = 0; j < CPL; ++j) po[j] = __float2bfloat16(o[j]);
        }
    }
}

extern "C" void kernel_launch(void* const* d_in, const int* in_sizes, int n_in,
                              void* d_out, int out_size, void* d_ws, size_t ws_size,
                              hipStream_t stream) {
    const void* x  = d_in[0];
    const void* ei = d_in[1];
    const void* W1 = d_in[2];
    const void* b1 = d_in[3];
    const void* W2 = d_in[4];
    const void* b2 = d_in[5];
    const void* W3 = d_in[6];
    const void* b3 = d_in[7];

    const int N = in_sizes[0] / 128;  // 50000
    const int E = in_sizes[1] / 2;    // 800000

    char* p = (char*)d_ws;
    auto take = [&](size_t bytes) {
        char* q = p;
        p += (bytes + 255) & ~(size_t)255;
        return q;
    };
    int*   flags = (int*)take(64);
    int*   cnt  = (int*)take((size_t)N * 4);
    int*   bsum = (int*)take(1024);
    int*   off  = (int*)take((size_t)(N + 1) * 4);
    int*   cur  = (int*)take((size_t)N * 4);
    float* dinv = (float*)take((size_t)N * 4);
    int*   csr  = (int*)take((size_t)E * 4);
    void*  bufA = (void*)take((size_t)N * 128 * 4);   // G: bf16 or f32
    float* bufB = (float*)take((size_t)N * 128 * 4);  // h: always f32
    (void)n_in; (void)out_size; (void)ws_size;

    const int nb = (N + 255) / 256;  // <= 256
    const int eb = (E + 255) / 256;

    detect_dtypes<<<1, 128, 0, stream>>>(x, ei, flags);
    hipMemsetAsync(cnt, 0, (size_t)N * 4, stream);
    count_edges<<<eb, 256, 0, stream>>>(ei, cnt, flags, E);
    deg_reduce<<<nb, 256, 0, stream>>>(cnt, bsum, N);
    scan_bsums<<<1, 256, 0, stream>>>(bsum, nb);
    write_off<<<nb, 256, 0, stream>>>(cnt, bsum, off, cur, dinv, N, E);
    fill_csr<<<eb, 256, 0, stream>>>(ei, cur, csr, flags, E);

    const int gb = (N + 15) / 16;
    const int ab = (N + 3) / 4;

    // Layer 1: G = dinv*(x@W1); h1 = relu(dinv*agg + b1) -> bufB (f32)
    gemm_scale<true, 128><<<gb, 256, 0, stream>>>(x, W1, dinv, bufA, flags, N);
    aggregate<2, true, true, false><<<ab, 256, 0, stream>>>(bufA, off, csr, dinv, b1, bufB, nullptr, 0, flags, N);
    // Layer 2: h2 -> bufB (f32, feeds layer 3) AND d_out[0 : N*128]
    gemm_scale<false, 128><<<gb, 256, 0, stream>>>(bufB, W2, dinv, bufA, flags, N);
    aggregate<2, true, true, true><<<ab, 256, 0, stream>>>(bufA, off, csr, dinv, b2, bufB, d_out, 0, flags, N);
    // Layer 3: 64 classes, no relu -> d_out[N*128 : N*192]
    gemm_scale<false, 64><<<gb, 256, 0, stream>>>(bufB, W3, dinv, bufA, flags, N);
    aggregate<1, false, false, true><<<ab, 256, 0, stream>>>(bufA, off, csr, dinv, b3, nullptr, d_out, (long long)N * 128, flags, N);
}

// Round 7
// 444.506 us; speedup vs baseline: 1.0056x; 1.0056x over previous
//
#include <hip/hip_runtime.h>
#include <hip/hip_bf16.h>

// GCN 3-layer forward on gfx950, dtype-robust.
// flags[0]=1 if floats are f32 (else bf16); flags[1]=1 if edges int64 (else int32).
// bf16 world: G (message buffer) stored bf16; aggregate uses quarter-wave
// gather: 16 lanes x dwordx4 cover one 256B row, so one wave-load fetches
// 4 edges (128-ch) / 8 edges (64-ch). Cross-group shfl_xor reduction per node.
// Outputs written with non-temporal stores (no L2 write-allocate pollution).

typedef float vf4 __attribute__((ext_vector_type(4)));
typedef unsigned vu4 __attribute__((ext_vector_type(4)));

__device__ __forceinline__ float tof(float v) { return v; }
__device__ __forceinline__ float tof(__hip_bfloat16 v) { return __bfloat162float(v); }
__device__ __forceinline__ float bits2f(unsigned u) {
    union { unsigned u; float f; } c; c.u = u; return c.f;
}
__device__ __forceinline__ unsigned short f2bfu(float v) {
    __hip_bfloat16 h = __float2bfloat16(v);
    union { __hip_bfloat16 h; unsigned short u; } c; c.h = h; return c.u;
}
__device__ __forceinline__ float bflo(unsigned d) { return bits2f(d << 16); }
__device__ __forceinline__ float bfhi(unsigned d) { return bits2f(d & 0xffff0000u); }

__global__ void detect_dtypes(const void* __restrict__ x,
                              const void* __restrict__ ei,
                              int* __restrict__ flags) {
    const int t = threadIdx.x;
    const int lane = t & 63;
    if (t < 64) {
        const unsigned short* p = (const unsigned short*)x;
        int e = (p[2 * (lane * 16)] >> 7) & 0xFF;
        unsigned long long m = __ballot(e < 100 || e > 140);
        if (lane == 0) flags[0] = (__popcll(m) > 16) ? 1 : 0;
    } else if (t < 128) {
        const int* p = (const int*)ei;
        unsigned long long m = __ballot(p[2 * (lane * 16) + 1] != 0);
        if (lane == 0) flags[1] = (__popcll(m) < 2) ? 1 : 0;
    }
}

__device__ __forceinline__ int edge_at(const void* ei, long long idx, bool i64) {
    return i64 ? (int)((const long long*)ei)[idx] : ((const int*)ei)[idx];
}

__global__ void count_edges(const void* __restrict__ ei, int* __restrict__ cnt,
                            const int* __restrict__ flags, int e) {
    int i = blockIdx.x * 256 + threadIdx.x;
    if (i < e) {
        const bool i64 = flags[1] != 0;
        atomicAdd(&cnt[edge_at(ei, (long long)e + i, i64)], 1);
    }
}

__global__ __launch_bounds__(256) void deg_reduce(const int* __restrict__ cnt,
                                                  int* __restrict__ bsum, int n) {
    __shared__ int sm[4];
    const int t = threadIdx.x;
    int i = blockIdx.x * 256 + t;
    int v = (i < n) ? cnt[i] : 0;
#pragma unroll
    for (int d = 32; d >= 1; d >>= 1) v += __shfl_down(v, d);
    if ((t & 63) == 0) sm[t >> 6] = v;
    __syncthreads();
    if (t == 0) bsum[blockIdx.x] = sm[0] + sm[1] + sm[2] + sm[3];
}

__global__ __launch_bounds__(256) void scan_bsums(int* __restrict__ bsum, int nb) {
    __shared__ int sm[256];
    const int t = threadIdx.x;
    sm[t] = (t < nb) ? bsum[t] : 0;
    __syncthreads();
#pragma unroll
    for (int d = 1; d < 256; d <<= 1) {
        int v = (t >= d) ? sm[t - d] : 0;
        __syncthreads();
        sm[t] += v;
        __syncthreads();
    }
    if (t < nb) bsum[t] = (t == 0) ? 0 : sm[t - 1];
}

__global__ __launch_bounds__(256) void write_off(const int* __restrict__ cnt,
                                                 const int* __restrict__ bsum,
                                                 int* __restrict__ off,
                                                 int* __restrict__ cur,
                                                 float* __restrict__ dinv,
                                                 int n, int e_total) {
    __shared__ int sm[256];
    const int t = threadIdx.x;
    const int i = blockIdx.x * 256 + t;
    const int c = (i < n) ? cnt[i] : 0;
    sm[t] = c;
    __syncthreads();
#pragma unroll
    for (int d = 1; d < 256; d <<= 1) {
        int v = (t >= d) ? sm[t - d] : 0;
        __syncthreads();
        sm[t] += v;
        __syncthreads();
    }
    if (i < n) {
        int o = bsum[blockIdx.x] + sm[t] - c;
        off[i] = o;
        cur[i] = o;
        dinv[i] = rsqrtf((float)(c + 1));
        if (i == n - 1) off[n] = e_total;
    }
}

__global__ void fill_csr(const void* __restrict__ ei, int* __restrict__ cur,
                         int* __restrict__ csr_src, const int* __restrict__ flags, int e) {
    int i = blockIdx.x * 256 + threadIdx.x;
    if (i < e) {
        const bool i64 = flags[1] != 0;
        int r = edge_at(ei, i, i64);
        int c = edge_at(ei, (long long)e + i, i64);
        int p = atomicAdd(&cur[c], 1);
        __builtin_nontemporal_store(r, &csr_src[p]);
    }
}

// G[i][c] = dinv[i] * sum_k X[i][k]*W[k][c]. 256 threads, 16 rows x COUT/blk.
template <bool XFLAG, int COUT>
__global__ __launch_bounds__(256) void gemm_scale(const void* __restrict__ Xv,
                                                  const void* __restrict__ Wv,
                                                  const float* __restrict__ dinv,
                                                  void* __restrict__ Gv,
                                                  const int* __restrict__ flags, int n) {
    constexpr int ROWS = 16;
    constexpr int KC = 64;
    __shared__ float wlds[KC * COUT];
    __shared__ float xlds[ROWS * 128];
    const int t = threadIdx.x;
    const int row0 = blockIdx.x * ROWS;
    const bool f32 = flags[0] != 0;
    const bool xf32 = XFLAG ? f32 : true;

    if (xf32) {
        const float* X = (const float*)Xv;
        for (int i = t; i < ROWS * 128; i += 256) {
            int r = i >> 7;
            xlds[i] = (row0 + r < n) ? X[(size_t)(row0 + r) * 128 + (i & 127)] : 0.f;
        }
    } else {
        const __hip_bfloat16* X = (const __hip_bfloat16*)Xv;
        for (int i = t; i < ROWS * 128; i += 256) {
            int r = i >> 7;
            xlds[i] = (row0 + r < n) ? tof(X[(size_t)(row0 + r) * 128 + (i & 127)]) : 0.f;
        }
    }

    float acc[8];
#pragma unroll
    for (int j = 0; j < 8; ++j) acc[j] = 0.f;

    const int c4 = (COUT == 128) ? ((t & 31) * 4) : ((t & 15) * 4);
    const int r0 = (COUT == 128) ? ((t >> 5) * 2) : (t >> 4);

    for (int kc = 0; kc < 128; kc += KC) {
        __syncthreads();
        if (f32) {
            const float* W = (const float*)Wv;
            for (int i = t; i < KC * COUT; i += 256)
                wlds[i] = W[(size_t)kc * COUT + i];
        } else {
            const __hip_bfloat16* W = (const __hip_bfloat16*)Wv;
            for (int i = t; i < KC * COUT; i += 256)
                wlds[i] = tof(W[(size_t)kc * COUT + i]);
        }
        __syncthreads();
#pragma unroll
        for (int k = 0; k < KC; ++k) {
            const float4 w = *(const float4*)&wlds[k * COUT + c4];
            if (COUT == 128) {
                float x0 = xlds[r0 * 128 + kc + k];
                float x1 = xlds[(r0 + 1) * 128 + kc + k];
                acc[0] += x0 * w.x; acc[1] += x0 * w.y;
                acc[2] += x0 * w.z; acc[3] += x0 * w.w;
                acc[4] += x1 * w.x; acc[5] += x1 * w.y;
                acc[6] += x1 * w.z; acc[7] += x1 * w.w;
            } else {
                float x0 = xlds[r0 * 128 + kc + k];
                acc[0] += x0 * w.x; acc[1] += x0 * w.y;
                acc[2] += x0 * w.z; acc[3] += x0 * w.w;
            }
        }
    }

    const int nr = (COUT == 128) ? 2 : 1;
#pragma unroll
    for (int rr = 0; rr < nr; ++rr) {
        int row = row0 + r0 + rr;
        if (row < n) {
            float d = dinv[row];
            float o0 = d * acc[rr * 4 + 0];
            float o1 = d * acc[rr * 4 + 1];
            float o2 = d * acc[rr * 4 + 2];
            float o3 = d * acc[rr * 4 + 3];
            if (f32) {
                float4 o = make_float4(o0, o1, o2, o3);
                *(float4*)&((float*)Gv)[(size_t)row * COUT + c4] = o;
            } else {
                ushort4 u;
                u.x = f2bfu(o0); u.y = f2bfu(o1);
                u.z = f2bfu(o2); u.w = f2bfu(o3);
                *(ushort4*)&((unsigned short*)Gv)[(size_t)row * COUT + c4] = u;
            }
        }
    }
}

// One wave per destination node. bf16 world: quarter-wave gather — row is
// (C/2) dwords; LPG lanes x 16B cover it; GROUPS=64/LPG edges per wave-load.
// Lane holds 8 channels (li*8..li*8+7). Self row masked to group 0.
template <int CPL, bool RELU, bool WWS, bool WOUT>
__global__ __launch_bounds__(256) void aggregate(const void* __restrict__ Gv,
                                                 const int* __restrict__ off,
                                                 const int* __restrict__ csr_src,
                                                 const float* __restrict__ dinv,
                                                 const void* __restrict__ bias,
                                                 float* __restrict__ Hf,
                                                 void* __restrict__ outp,
                                                 long long out_off,
                                                 const int* __restrict__ flags, int n) {
    const int gw = (int)((blockIdx.x * 256u + threadIdx.x) >> 6);
    const int lane = threadIdx.x & 63;
    if (gw >= n) return;
    constexpr int C = CPL * 64;
    const bool f32 = flags[0] != 0;
    const int e0 = off[gw];
    const int e1 = off[gw + 1];
    const float d = dinv[gw];

    if (!f32) {
        // ---------------- bf16 world: quarter-wave gather ----------------
        constexpr int LPG = (CPL == 2) ? 16 : 8;   // lanes per group
        constexpr int GROUPS = 64 / LPG;           // edges per wave-load
        constexpr int RD = C / 2;                  // row dwords
        const int g = lane / LPG;
        const int li = lane % LPG;
        const unsigned* Gd = (const unsigned*)Gv;

        float acc[8];
        {   // self-loop init, group 0 only (others would double-count)
            uint4 sv = *(const uint4*)&Gd[(size_t)gw * RD + li * 4];
            const float ms = (g == 0) ? 1.f : 0.f;
            acc[0] = ms * bflo(sv.x); acc[1] = ms * bfhi(sv.x);
            acc[2] = ms * bflo(sv.y); acc[3] = ms * bfhi(sv.y);
            acc[4] = ms * bflo(sv.z); acc[5] = ms * bfhi(sv.z);
            acc[6] = ms * bflo(sv.w); acc[7] = ms * bfhi(sv.w);
        }

        for (int bs = e0; bs < e1; bs += 64) {
            const int cnt = min(64, e1 - bs);
            const int myidx = (bs + lane < e1) ? csr_src[bs + lane] : 0;
            for (int j = 0; j < cnt; j += 2 * GROUPS) {
#pragma unroll
                for (int u = 0; u < 2; ++u) {
                    const int eb = j + u * GROUPS + g;
                    const int jj = min(eb, cnt - 1);
                    const int s = __shfl(myidx, jj);
                    const float m = (eb < cnt) ? 1.f : 0.f;
                    uint4 v = *(const uint4*)&Gd[(size_t)s * RD + li * 4];
                    acc[0] = fmaf(m, bflo(v.x), acc[0]);
                    acc[1] = fmaf(m, bfhi(v.x), acc[1]);
                    acc[2] = fmaf(m, bflo(v.y), acc[2]);
                    acc[3] = fmaf(m, bfhi(v.y), acc[3]);
                    acc[4] = fmaf(m, bflo(v.z), acc[4]);
                    acc[5] = fmaf(m, bfhi(v.z), acc[5]);
                    acc[6] = fmaf(m, bflo(v.w), acc[6]);
                    acc[7] = fmaf(m, bfhi(v.w), acc[7]);
                }
            }
        }

        // reduce partial sums across groups
#pragma unroll
        for (int mask = LPG; mask <= 32; mask <<= 1)
#pragma unroll
            for (int i = 0; i < 8; ++i) acc[i] += __shfl_xor(acc[i], mask);

        // epilogue: all lanes compute; group 0 stores
        uint4 bv = *(const uint4*)&((const unsigned*)bias)[li * 4];
        float o[8];
        o[0] = d * acc[0] + bflo(bv.x); o[1] = d * acc[1] + bfhi(bv.x);
        o[2] = d * acc[2] + bflo(bv.y); o[3] = d * acc[3] + bfhi(bv.y);
        o[4] = d * acc[4] + bflo(bv.z); o[5] = d * acc[5] + bfhi(bv.z);
        o[6] = d * acc[6] + bflo(bv.w); o[7] = d * acc[7] + bfhi(bv.w);
        if (RELU) {
#pragma unroll
            for (int i = 0; i < 8; ++i) o[i] = fmaxf(o[i], 0.f);
        }
        if (g == 0) {
            if constexpr (WWS) {
                vf4* p0 = (vf4*)&Hf[(size_t)gw * C + li * 8];
                vf4 w0 = {o[0], o[1], o[2], o[3]};
                vf4 w1 = {o[4], o[5], o[6], o[7]};
                __builtin_nontemporal_store(w0, p0);
                __builtin_nontemporal_store(w1, p0 + 1);
            }
            if constexpr (WOUT) {
                unsigned* ob = (unsigned*)outp + (out_off >> 1) + (size_t)gw * RD + li * 4;
                vu4 u;
                u.x = (unsigned)f2bfu(o[0]) | ((unsigned)f2bfu(o[1]) << 16);
                u.y = (unsigned)f2bfu(o[2]) | ((unsigned)f2bfu(o[3]) << 16);
                u.z = (unsigned)f2bfu(o[4]) | ((unsigned)f2bfu(o[5]) << 16);
                u.w = (unsigned)f2bfu(o[6]) | ((unsigned)f2bfu(o[7]) << 16);
                __builtin_nontemporal_store(u, (vu4*)ob);
            }
        }
    } else {
        // ---------------- f32 world fallback (full-wave, 8-wide) ----------------
        const float* Gf = (const float*)Gv;
        const int col = lane * CPL;
        const size_t base = (size_t)gw * C + col;
        float a0, a1;
        if constexpr (CPL == 2) {
            float2 v = *(const float2*)&Gf[base];
            a0 = v.x; a1 = v.y;
        } else {
            a0 = Gf[base]; a1 = 0.f;
        }
        for (int bs = e0; bs < e1; bs += 64) {
            const int cnt = min(64, e1 - bs);
            const int myidx = (bs + lane < e1) ? csr_src[bs + lane] : 0;
            for (int j = 0; j < cnt; j += 8) {
#pragma unroll
                for (int k = 0; k < 8; ++k) {
                    const int jj = min(j + k, cnt - 1);
                    const int s = __shfl(myidx, jj);
                    const float m = (j + k < cnt) ? 1.f : 0.f;
                    if constexpr (CPL == 2) {
                        float2 v = *(const float2*)&Gf[(size_t)s * C + col];
                        a0 = fmaf(m, v.x, a0);
                        a1 = fmaf(m, v.y, a1);
                    } else {
                        float v = Gf[(size_t)s * C + col];
                        a0 = fmaf(m, v, a0);
                    }
                }
            }
        }
        float accs[2] = {a0, a1};
        float o[CPL];
#pragma unroll
        for (int j = 0; j < CPL; ++j) {
            float bv = ((const float*)bias)[col + j];
            o[j] = d * accs[j] + bv;
            if (RELU) o[j] = fmaxf(o[j], 0.f);
        }
        if constexpr (WWS) {
            if constexpr (CPL == 2)
                *(float2*)&Hf[base] = make_float2(o[0], o[1]);
            else
                Hf[base] = o[0];
        }
        if constexpr (WOUT) {
            float* po = (float*)outp + out_off + base;
#pragma unroll
            for (int j = 0; j < CPL; ++j) po[j] = o[j];
        }
    }
}

extern "C" void kernel_launch(void* const* d_in, const int* in_sizes, int n_in,
                              void* d_out, int out_size, void* d_ws, size_t ws_size,
                              hipStream_t stream) {
    const void* x  = d_in[0];
    const void* ei = d_in[1];
    const void* W1 = d_in[2];
    const void* b1 = d_in[3];
    const void* W2 = d_in[4];
    const void* b2 = d_in[5];
    const void* W3 = d_in[6];
    const void* b3 = d_in[7];

    const int N = in_sizes[0] / 128;  // 50000
    const int E = in_sizes[1] / 2;    // 800000

    char* p = (char*)d_ws;
    auto take = [&](size_t bytes) {
        char* q = p;
        p += (bytes + 255) & ~(size_t)255;
        return q;
    };
    int*   flags = (int*)take(64);
    int*   cnt  = (int*)take((size_t)N * 4);
    int*   bsum = (int*)take(1024);
    int*   off  = (int*)take((size_t)(N + 1) * 4);
    int*   cur  = (int*)take((size_t)N * 4);
    float* dinv = (float*)take((size_t)N * 4);
    int*   csr  = (int*)take((size_t)E * 4);
    void*  bufA = (void*)take((size_t)N * 128 * 4);   // G: bf16 or f32
    float* bufB = (float*)take((size_t)N * 128 * 4);  // h: always f32
    (void)n_in; (void)out_size; (void)ws_size;

    const int nb = (N + 255) / 256;  // <= 256
    const int eb = (E + 255) / 256;

    detect_dtypes<<<1, 128, 0, stream>>>(x, ei, flags);
    hipMemsetAsync(cnt, 0, (size_t)N * 4, stream);
    count_edges<<<eb, 256, 0, stream>>>(ei, cnt, flags, E);
    deg_reduce<<<nb, 256, 0, stream>>>(cnt, bsum, N);
    scan_bsums<<<1, 256, 0, stream>>>(bsum, nb);
    write_off<<<nb, 256, 0, stream>>>(cnt, bsum, off, cur, dinv, N, E);
    fill_csr<<<eb, 256, 0, stream>>>(ei, cur, csr, flags, E);

    const int gb = (N + 15) / 16;
    const int ab = (N + 3) / 4;

    // Layer 1: G = dinv*(x@W1); h1 = relu(dinv*agg + b1) -> bufB (f32)
    gemm_scale<true, 128><<<gb, 256, 0, stream>>>(x, W1, dinv, bufA, flags, N);
    aggregate<2, true, true, false><<<ab, 256, 0, stream>>>(bufA, off, csr, dinv, b1, bufB, nullptr, 0, flags, N);
    // Layer 2: h2 -> bufB (f32, feeds layer 3) AND d_out[0 : N*128]
    gemm_scale<false, 128><<<gb, 256, 0, stream>>>(bufB, W2, dinv, bufA, flags, N);
    aggregate<2, true, true, true><<<ab, 256, 0, stream>>>(bufA, off, csr, dinv, b2, bufB, d_out, 0, flags, N);
    // Layer 3: 64 classes, no relu -> d_out[N*128 : N*192]
    gemm_scale<false, 64><<<gb, 256, 0, stream>>>(bufB, W3, dinv, bufA, flags, N);
    aggregate<1, false, false, true><<<ab, 256, 0, stream>>>(bufA, off, csr, dinv, b3, nullptr, d_out, (long long)N * 128, flags, N);
}